// Round 1
// baseline (3554.236 us; speedup 1.0000x reference)
//
#include <hip/hip_runtime.h>

#define SEQL 4096
#define NB   256
#define NH   64
// rows = SEQL*NB = 1048576

// Kernel A: xp[r][h] = dot(w_ih[h][:], x[r][:]) + b_ih[h] + b_hh[h], written into d_out.
// One thread per row. w_ih/bias indices are wave-uniform -> expect scalar (s_load) path.
__global__ __launch_bounds__(256) void xproj(const float* __restrict__ x,
                                             const float* __restrict__ w_ih,
                                             const float* __restrict__ b_ih,
                                             const float* __restrict__ b_hh,
                                             float* __restrict__ out) {
  size_t r = (size_t)blockIdx.x * 256 + threadIdx.x;
  const float4* xr = (const float4*)(x + r * NH);
  float4 xv[16];
#pragma unroll
  for (int k = 0; k < 16; ++k) xv[k] = xr[k];
  float4* outr = (float4*)(out + r * NH);
#pragma unroll 1   // keep code size sane; inner loop fully unrolled
  for (int hg = 0; hg < 16; ++hg) {
    int h0 = hg * 4;
    float a0 = b_ih[h0 + 0] + b_hh[h0 + 0];
    float a1 = b_ih[h0 + 1] + b_hh[h0 + 1];
    float a2 = b_ih[h0 + 2] + b_hh[h0 + 2];
    float a3 = b_ih[h0 + 3] + b_hh[h0 + 3];
    const float* w0 = w_ih + (size_t)(h0 + 0) * NH;
    const float* w1 = w_ih + (size_t)(h0 + 1) * NH;
    const float* w2 = w_ih + (size_t)(h0 + 2) * NH;
    const float* w3 = w_ih + (size_t)(h0 + 3) * NH;
#pragma unroll
    for (int k = 0; k < 64; ++k) {
      float xk = ((const float*)xv)[k];
      a0 = fmaf(w0[k], xk, a0);
      a1 = fmaf(w1[k], xk, a1);
      a2 = fmaf(w2[k], xk, a2);
      a3 = fmaf(w3[k], xk, a3);
    }
    outr[hg] = make_float4(a0, a1, a2, a3);
  }
}

// Kernel B: sequential scan. One block (one wave, 64 lanes) per batch row.
// Lane i owns output h[i] and W_hh row i in 64 VGPRs; h broadcast each step via LDS.
// Reads xp from out[s][b][:] and overwrites the same slot with h_s (in-place).
__global__ __launch_bounds__(64) void rnn_rec(const float* __restrict__ w_hh,
                                              float* __restrict__ out) {
  __shared__ __align__(16) float hs[NH];
  const int b = blockIdx.x;
  const int i = threadIdx.x;

  float4 w[16];
  const float4* wr = (const float4*)(w_hh + (size_t)i * NH);
#pragma unroll
  for (int k = 0; k < 16; ++k) w[k] = wr[k];

  hs[i] = 0.f;
  __syncthreads();

  const size_t step = (size_t)NB * NH;           // 16384 floats per timestep
  float* p = out + (size_t)b * NH + i;           // this lane's xp/out column
  float xp0 = p[0];                              // s = 0
  float xp1 = p[step];                           // s = 1
  const float4* h4 = (const float4*)hs;

#pragma unroll 1
  for (int s = 0; s < SEQL; ++s) {
    // prefetch 2 steps ahead (global latency ~600cy > step time)
    float xp2 = (s + 2 < SEQL) ? p[(size_t)(s + 2) * step] : 0.f;

    float a0 = xp0, a1 = 0.f, a2 = 0.f, a3 = 0.f;
#pragma unroll
    for (int j = 0; j < 16; ++j) {
      float4 hv = h4[j];                         // uniform-address LDS broadcast
      a0 = fmaf(w[j].x, hv.x, a0);
      a1 = fmaf(w[j].y, hv.y, a1);
      a2 = fmaf(w[j].z, hv.z, a2);
      a3 = fmaf(w[j].w, hv.w, a3);
    }
    float z = (a0 + a1) + (a2 + a3);
    z = fminf(15.f, fmaxf(-15.f, z));
    float t = __builtin_amdgcn_exp2f(z * 2.885390081777927f);   // e^(2z)
    float hn = (t - 1.f) * __builtin_amdgcn_rcpf(t + 1.f);      // tanh(z)

    __syncthreads();            // everyone done reading hs (old h)
    hs[i] = hn;
    p[(size_t)s * step] = hn;   // overwrite consumed xp slot with output
    __syncthreads();            // new h visible

    xp0 = xp1;
    xp1 = xp2;
  }
}

extern "C" void kernel_launch(void* const* d_in, const int* in_sizes, int n_in,
                              void* d_out, int out_size, void* d_ws, size_t ws_size,
                              hipStream_t stream) {
  const float* x    = (const float*)d_in[0];
  const float* w_ih = (const float*)d_in[1];
  const float* w_hh = (const float*)d_in[2];
  const float* b_ih = (const float*)d_in[3];
  const float* b_hh = (const float*)d_in[4];
  float* out = (float*)d_out;

  xproj<<<dim3(4096), dim3(256), 0, stream>>>(x, w_ih, b_ih, b_hh, out);
  rnn_rec<<<dim3(NB), dim3(NH), 0, stream>>>(w_hh, out);
}